// Round 1
// baseline (121.115 us; speedup 1.0000x reference)
//
#include <hip/hip_runtime.h>
#include <cstdint>

// Problem constants (fixed by setup_inputs): (8, 4096, 6) fp32 both inputs.
#define NB 8
#define NP 4096
#define THREADS 256
#define Q 4                    // query points per thread (registers)
#define SEG 16                 // target-dimension split across blocks
#define TSEG (NP / SEG)        // 256 targets per LDS tile
#define CHUNK (THREADS * Q)    // 1024 queries per block
#define NCHUNK (NP / CHUNK)    // 4

// Packed best = (float_bits(dist) & 0xFFFFF000) | target_idx (12 bits).
// dist >= 0 so float bits order as uint; min picks min dist, ties -> lowest idx
// (matches argmin first-occurrence). 12 stolen mantissa bits: <=2^-11 rel err.

__global__ __launch_bounds__(THREADS) void chamfer_argmin(
    const float* __restrict__ xyz1, const float* __restrict__ xyz2,
    unsigned int* __restrict__ best)
{
    __shared__ float4 tgt[TSEG];

    unsigned int x = blockIdx.x;                 // (((dir*8+b)*NCHUNK+chunk)*SEG+seg)
    int seg   = x & (SEG - 1);
    int chunk = (x >> 4) & (NCHUNK - 1);
    int b     = (x >> 6) & 7;
    int dir   = x >> 9;

    const float* qset = dir ? xyz2 : xyz1;
    const float* tset = dir ? xyz1 : xyz2;

    // Stage this segment's targets into LDS (one point per thread).
    int tbase = seg * TSEG;
    {
        int t = tbase + threadIdx.x;
        const float* src = tset + ((size_t)b * NP + t) * 6;
        tgt[threadIdx.x] = make_float4(src[0], src[1], src[2], 0.0f);
    }
    __syncthreads();

    // Load Q query points into registers (coalesced: stride THREADS between qi).
    float qx[Q], qy[Q], qz[Q];
    unsigned int bst[Q];
    int qbase = chunk * CHUNK + threadIdx.x;
    #pragma unroll
    for (int i = 0; i < Q; ++i) {
        const float* src = qset + ((size_t)b * NP + qbase + i * THREADS) * 6;
        qx[i] = src[0]; qy[i] = src[1]; qz[i] = src[2];
        bst[i] = 0xFFFFFFFFu;
    }

    // Inner scan: LDS read is wave-uniform (broadcast, conflict-free),
    // amortized over Q queries. 1 v_min_u32 per candidate via packed trick.
    #pragma unroll 4
    for (int k = 0; k < TSEG; ++k) {
        float4 t = tgt[k];
        unsigned int jb = (unsigned int)(tbase + k);
        #pragma unroll
        for (int i = 0; i < Q; ++i) {
            float dx = t.x - qx[i];
            float dy = t.y - qy[i];
            float dz = t.z - qz[i];
            float d = dx * dx + dy * dy + dz * dz;
            unsigned int c = (__float_as_uint(d) & 0xFFFFF000u) | jb;
            bst[i] = bst[i] < c ? bst[i] : c;
        }
    }

    unsigned int* slot = best + ((size_t)dir * NB + b) * NP + qbase;
    #pragma unroll
    for (int i = 0; i < Q; ++i)
        atomicMin(slot + i * THREADS, bst[i]);
}

__global__ __launch_bounds__(256) void chamfer_finish(
    const float* __restrict__ xyz1, const float* __restrict__ xyz2,
    const unsigned int* __restrict__ best, float* __restrict__ out)
{
    int gid = blockIdx.x * 256 + threadIdx.x;    // 0 .. 2*NB*NP-1
    int q   = gid & (NP - 1);
    int b   = (gid >> 12) & 7;
    int dir = gid >> 15;
    const float* qset = dir ? xyz2 : xyz1;
    const float* tset = dir ? xyz1 : xyz2;

    unsigned int p = best[gid];
    float dist = __uint_as_float(p & 0xFFFFF000u);
    int j = (int)(p & 0xFFFu);

    const float* nq = qset + ((size_t)b * NP + q) * 6 + 3;
    const float* nt = tset + ((size_t)b * NP + j) * 6 + 3;
    float ax = nq[0], ay = nq[1], az = nq[2];
    float bx = nt[0], by = nt[1], bz = nt[2];

    float na = fmaxf(sqrtf(ax * ax + ay * ay + az * az), 1e-12f);
    float nb = fmaxf(sqrtf(bx * bx + by * by + bz * bz), 1e-12f);
    float ra = 1.0f / na, rb = 1.0f / nb;
    float dx = ax * ra - bx * rb;
    float dy = ay * ra - by * rb;
    float dz = az * ra - bz * rb;
    float nd = dx * dx + dy * dy + dz * dz;

    // mean over 8*4096 for each of {dist, nd} per direction; sum of 4 means.
    float contrib = (dist + nd) * (1.0f / 32768.0f);

    // wave64 reduce, then cross-wave via LDS, one atomic per block.
    for (int off = 32; off > 0; off >>= 1)
        contrib += __shfl_down(contrib, off, 64);
    __shared__ float wsum[4];
    if ((threadIdx.x & 63) == 0) wsum[threadIdx.x >> 6] = contrib;
    __syncthreads();
    if (threadIdx.x == 0)
        atomicAdd(out, wsum[0] + wsum[1] + wsum[2] + wsum[3]);
}

extern "C" void kernel_launch(void* const* d_in, const int* in_sizes, int n_in,
                              void* d_out, int out_size, void* d_ws, size_t ws_size,
                              hipStream_t stream) {
    const float* xyz1 = (const float*)d_in[0];
    const float* xyz2 = (const float*)d_in[1];
    float* out = (float*)d_out;
    unsigned int* best = (unsigned int*)d_ws;    // 2*NB*NP u32 = 256 KB

    hipMemsetAsync(d_ws, 0xFF, (size_t)2 * NB * NP * sizeof(unsigned int), stream);
    hipMemsetAsync(d_out, 0, sizeof(float), stream);

    chamfer_argmin<<<2 * NB * NCHUNK * SEG, THREADS, 0, stream>>>(xyz1, xyz2, best);
    chamfer_finish<<<(2 * NB * NP) / 256, 256, 0, stream>>>(xyz1, xyz2, best, out);
}

// Round 2
// 94.287 us; speedup vs baseline: 1.2845x; 1.2845x over previous
//
#include <hip/hip_runtime.h>
#include <cstdint>

// Problem constants (fixed by setup_inputs): (8, 4096, 6) fp32 both inputs.
#define NB 8
#define NP 4096
#define THREADS 256
#define Q 4                    // query points per thread (registers)
#define CHUNK (THREADS * Q)    // 1024 queries per block
#define NCHUNK (NP / CHUNK)    // 4

// Per-pair inner loop: s = q·t - 0.5|t|^2 (3 FMA, .w of LDS float4 holds the
// -0.5|t|^2 bias), exact fp32 max+argmax tracking (cmp/cndmask/max = 3 inst).
// Block epilogue reconstructs d = |q|^2 - 2s (abs err ~1e-6) and writes a
// packed partial (float bits of d chopped to 20 bits | 12-bit target idx) to a
// private slot -- no atomics, no 0xFF pre-init. finish min-reduces partials.

template <int SEGV>
__global__ __launch_bounds__(THREADS) void chamfer_argmin(
    const float* __restrict__ xyz1, const float* __restrict__ xyz2,
    unsigned int* __restrict__ part)
{
    const int TSEG = NP / SEGV;
    __shared__ float4 tgt[NP / 16];          // max TSEG we instantiate (SEG>=16)

    unsigned int x = blockIdx.x;             // (((dir*8+b)*NCHUNK+chunk)*SEG+seg)
    int seg   = x & (SEGV - 1);
    int chunk = (x / SEGV) & (NCHUNK - 1);
    int b     = (x / (SEGV * NCHUNK)) & 7;
    int dir   = x / (SEGV * NCHUNK * 8);

    const float* qset = dir ? xyz2 : xyz1;
    const float* tset = dir ? xyz1 : xyz2;

    // Stage this segment's targets into LDS with the -0.5|t|^2 bias in .w.
    int tbase = seg * TSEG;
    for (int t0 = threadIdx.x; t0 < TSEG; t0 += THREADS) {
        const float* src = tset + ((size_t)b * NP + tbase + t0) * 6;
        float tx = src[0], ty = src[1], tz = src[2];
        tgt[t0] = make_float4(tx, ty, tz, -0.5f * (tx * tx + ty * ty + tz * tz));
    }
    __syncthreads();

    // Load Q query points into registers (stride THREADS between qi).
    float qx[Q], qy[Q], qz[Q], qq[Q], bs[Q];
    unsigned int bi[Q];
    int qbase = chunk * CHUNK + threadIdx.x;
    #pragma unroll
    for (int i = 0; i < Q; ++i) {
        const float* src = qset + ((size_t)b * NP + qbase + i * THREADS) * 6;
        qx[i] = src[0]; qy[i] = src[1]; qz[i] = src[2];
        qq[i] = qx[i] * qx[i] + qy[i] * qy[i] + qz[i] * qz[i];
        bs[i] = -3.4e38f;
        bi[i] = 0u;
    }

    // Inner scan: LDS read wave-uniform (broadcast), 3 FMA + 3 select per pair.
    #pragma unroll 4
    for (int k = 0; k < TSEG; ++k) {
        float4 t = tgt[k];
        unsigned int jb = (unsigned int)(tbase + k);
        #pragma unroll
        for (int i = 0; i < Q; ++i) {
            float s = fmaf(t.x, qx[i], fmaf(t.y, qy[i], fmaf(t.z, qz[i], t.w)));
            if (s > bs[i]) { bs[i] = s; bi[i] = jb; }   // strict > : first-idx ties
        }
    }

    // Private partial slot per (dir,b,seg,query): coalesced plain stores.
    unsigned int* slot =
        part + (((size_t)(dir * NB + b) * SEGV + seg) * NP) + qbase;
    #pragma unroll
    for (int i = 0; i < Q; ++i) {
        float d = fmaxf(fmaf(-2.0f, bs[i], qq[i]), 0.0f);
        slot[i * THREADS] = (__float_as_uint(d) & 0xFFFFF000u) | bi[i];
    }
}

template <int SEGV>
__global__ __launch_bounds__(256) void chamfer_finish(
    const float* __restrict__ xyz1, const float* __restrict__ xyz2,
    const unsigned int* __restrict__ part, float* __restrict__ out)
{
    int gid = blockIdx.x * 256 + threadIdx.x;    // 0 .. 2*NB*NP-1
    int q   = gid & (NP - 1);
    int db  = gid >> 12;                          // dir*8+b
    int b   = db & 7;
    int dir = db >> 3;

    // Min-reduce packed partials across segments (lanes contiguous in q ->
    // each iteration is a coalesced 256B wave read, L2-resident).
    const unsigned int* base = part + ((size_t)db * SEGV) * NP + q;
    unsigned int p = 0xFFFFFFFFu;
    #pragma unroll
    for (int s = 0; s < SEGV; ++s) p = min(p, base[(size_t)s * NP]);

    const float* qset = dir ? xyz2 : xyz1;
    const float* tset = dir ? xyz1 : xyz2;

    float dist = __uint_as_float(p & 0xFFFFF000u);
    int j = (int)(p & 0xFFFu);

    const float* nq = qset + ((size_t)b * NP + q) * 6 + 3;
    const float* nt = tset + ((size_t)b * NP + j) * 6 + 3;
    float ax = nq[0], ay = nq[1], az = nq[2];
    float bx = nt[0], by = nt[1], bz = nt[2];

    float na = fmaxf(sqrtf(ax * ax + ay * ay + az * az), 1e-12f);
    float nb = fmaxf(sqrtf(bx * bx + by * by + bz * bz), 1e-12f);
    float ra = 1.0f / na, rb = 1.0f / nb;
    float dx = ax * ra - bx * rb;
    float dy = ay * ra - by * rb;
    float dz = az * ra - bz * rb;
    float nd = dx * dx + dy * dy + dz * dz;

    // mean over 8*4096 for each of {dist, nd} per direction; sum of 4 means.
    float contrib = (dist + nd) * (1.0f / 32768.0f);

    for (int off = 32; off > 0; off >>= 1)
        contrib += __shfl_down(contrib, off, 64);
    __shared__ float wsum[4];
    if ((threadIdx.x & 63) == 0) wsum[threadIdx.x >> 6] = contrib;
    __syncthreads();
    if (threadIdx.x == 0)
        atomicAdd(out, wsum[0] + wsum[1] + wsum[2] + wsum[3]);
}

extern "C" void kernel_launch(void* const* d_in, const int* in_sizes, int n_in,
                              void* d_out, int out_size, void* d_ws, size_t ws_size,
                              hipStream_t stream) {
    const float* xyz1 = (const float*)d_in[0];
    const float* xyz2 = (const float*)d_in[1];
    float* out = (float*)d_out;
    unsigned int* part = (unsigned int*)d_ws;

    hipMemsetAsync(d_out, 0, sizeof(float), stream);

    size_t need32 = (size_t)2 * NB * 32 * NP * sizeof(unsigned int);  // 8 MB
    if (ws_size >= need32) {
        chamfer_argmin<32><<<2 * NB * NCHUNK * 32, THREADS, 0, stream>>>(xyz1, xyz2, part);
        chamfer_finish<32><<<(2 * NB * NP) / 256, 256, 0, stream>>>(xyz1, xyz2, part, out);
    } else {
        chamfer_argmin<16><<<2 * NB * NCHUNK * 16, THREADS, 0, stream>>>(xyz1, xyz2, part);
        chamfer_finish<16><<<(2 * NB * NP) / 256, 256, 0, stream>>>(xyz1, xyz2, part, out);
    }
}